// Round 2
// baseline (807.154 us; speedup 1.0000x reference)
//
#include <hip/hip_runtime.h>

#define Bn 4
#define Cn 64
#define Hn 128
#define Wn 128
#define HWn (Hn*Wn)          // 16384
#define NPIX (Bn*HWn)        // 65536
#define KKn 9
#define NOFF 18
#define EPSf 1e-5f

// ws layout (float element offsets)
#define OFF_XT    0u
#define OFF_DWT   4194304u
#define OFF_GEOM  8388608u
#define OFF_WT    9568256u        // 8388608 + 1179648
#define OFF_SSUM  9605120u        // + 36864
#define OFF_SSQ   9605184u
#define OFF_SCALE 9605248u
#define OFF_SHIFT 9605312u

// ---------------------------------------------------------------------------
// K1: depthwise 3x3 conv + bias -> DWT (NHWC), and x -> XT (NHWC)
__global__ __launch_bounds__(128) void k1_dw_transpose(
    const float* __restrict__ x, const float* __restrict__ dw_w,
    const float* __restrict__ dw_b, float* __restrict__ XT,
    float* __restrict__ DWT)
{
  int p = blockIdx.x * 128 + threadIdx.x;
  int b = p >> 14; int sp = p & 16383; int h = sp >> 7; int w = sp & 127;

  int so[9]; float mval[9];
  #pragma unroll
  for (int t = 0; t < 9; t++) {
    int dy = t / 3 - 1, dx = t % 3 - 1;
    int hh = h + dy, ww = w + dx;
    bool v = (hh >= 0) && (hh < Hn) && (ww >= 0) && (ww < Wn);
    int hc = v ? hh : h; int wc = v ? ww : w;
    so[t] = hc * Wn + wc;
    mval[t] = v ? 1.f : 0.f;
  }
  const float* xb = x + (size_t)b * Cn * HWn;
  for (int c0 = 0; c0 < Cn; c0 += 4) {
    float xcv[4], dwv[4];
    #pragma unroll
    for (int j = 0; j < 4; j++) {
      int c = c0 + j;
      const float* xc = xb + (size_t)c * HWn;
      float acc = dw_b[c];
      #pragma unroll
      for (int t = 0; t < 9; t++) {
        acc += (mval[t] * xc[so[t]]) * dw_w[c * 9 + t];
      }
      dwv[j] = acc;
      xcv[j] = xc[sp];
    }
    *(float4*)(&XT [(size_t)p * 64 + c0]) = make_float4(xcv[0], xcv[1], xcv[2], xcv[3]);
    *(float4*)(&DWT[(size_t)p * 64 + c0]) = make_float4(dwv[0], dwv[1], dwv[2], dwv[3]);
  }
}

// ---------------------------------------------------------------------------
// K_stats: per-channel sum / sumsq over DWT
__global__ __launch_bounds__(256) void k_stats(const float* __restrict__ DWT,
    float* __restrict__ ssum, float* __restrict__ ssq)
{
  int t = threadIdx.x; int c = t & 63; int g = t >> 6;
  float s = 0.f, q = 0.f;
  for (int p = blockIdx.x * 4 + g; p < NPIX; p += gridDim.x * 4) {
    float v = DWT[(size_t)p * 64 + c];
    s += v; q += v * v;
  }
  __shared__ float ls[2][256];
  ls[0][t] = s; ls[1][t] = q;
  __syncthreads();
  if (t < 64) {
    float s0 = ls[0][t] + ls[0][t + 64] + ls[0][t + 128] + ls[0][t + 192];
    float q0 = ls[1][t] + ls[1][t + 64] + ls[1][t + 128] + ls[1][t + 192];
    atomicAdd(&ssum[t], s0);
    atomicAdd(&ssq[t], q0);
  }
}

// ---------------------------------------------------------------------------
// K2: finalize BN -> scale/shift per channel
__global__ void k2_finalize(const float* __restrict__ ssum, const float* __restrict__ ssq,
    const float* __restrict__ gamma, const float* __restrict__ beta,
    float* __restrict__ scale, float* __restrict__ shift)
{
  int c = threadIdx.x;
  float n = (float)NPIX;
  float mean = ssum[c] / n;
  float var = ssq[c] / n - mean * mean;
  float sc = gamma[c] * rsqrtf(var + EPSf);
  scale[c] = sc;
  shift[c] = beta[c] - mean * sc;
}

// ---------------------------------------------------------------------------
// K_wt: deform_w (o,c,kk) -> WT[kk][o][c]
__global__ __launch_bounds__(256) void k_wt(const float* __restrict__ dwf,
                                            float* __restrict__ WT)
{
  int t = blockIdx.x * 256 + threadIdx.x;
  if (t >= 64 * 64 * 9) return;
  int c = t & 63; int o = (t >> 6) & 63; int kk = t >> 12;
  WT[t] = dwf[(o * 64 + c) * 9 + kk];
}

// ---------------------------------------------------------------------------
// K3: offsets (18 per pixel) -> sample coordinates GEOM[p][2*kk + {0,1}]
__global__ __launch_bounds__(256) void k3_offsets(const float* __restrict__ DWT,
    const float* __restrict__ scale, const float* __restrict__ shift,
    const float* __restrict__ pw_w, const float* __restrict__ pw_b,
    float* __restrict__ GEOM)
{
  int p = blockIdx.x * 256 + threadIdx.x;
  int sp = p & 16383; int h = sp >> 7; int w = sp & 127;
  float off[NOFF];
  #pragma unroll
  for (int o = 0; o < NOFF; o++) off[o] = pw_b[o];
  const float4* dp = (const float4*)(DWT + (size_t)p * 64);
  #pragma unroll
  for (int c4 = 0; c4 < 16; c4++) {
    float4 d = dp[c4];
    int c = c4 * 4;
    float x0 = d.x * scale[c]     + shift[c];
    float x1 = d.y * scale[c + 1] + shift[c + 1];
    float x2 = d.z * scale[c + 2] + shift[c + 2];
    float x3 = d.w * scale[c + 3] + shift[c + 3];
    #pragma unroll
    for (int o = 0; o < NOFF; o++) {
      const float* pw = pw_w + o * 64 + c;
      off[o] += pw[0] * x0 + pw[1] * x1 + pw[2] * x2 + pw[3] * x3;
    }
  }
  #pragma unroll
  for (int kk = 0; kk < KKn; kk++) {
    float py = (float)h - 1.f + (float)(kk / 3) + off[2 * kk];
    float px = (float)w - 1.f + (float)(kk % 3) + off[2 * kk + 1];
    GEOM[(size_t)p * NOFF + 2 * kk]     = py;
    GEOM[(size_t)p * NOFF + 2 * kk + 1] = px;
  }
}

// ---------------------------------------------------------------------------
// K4: bilinear sample + deform matvec + epilogue (x_deform + x_dw + x*skip)
__global__ __launch_bounds__(128) void k4_deform(
    const float* __restrict__ XT, const float* __restrict__ DWT,
    const float* __restrict__ GEOM, const float* __restrict__ WT,
    const float* __restrict__ scale, const float* __restrict__ shift,
    const float* __restrict__ deform_b, const float* __restrict__ skip_scale,
    float* __restrict__ out)
{
  int lane = threadIdx.x & 63;
  int obase = __builtin_amdgcn_readfirstlane((threadIdx.x >> 6) * 32);
  int p = blockIdx.x * 64 + lane;
  int b = p >> 14; int sp = p & 16383;

  float acc[32];
  #pragma unroll
  for (int o = 0; o < 32; o++) acc[o] = deform_b[obase + o];

  const size_t pbase = (size_t)b * HWn * 64;

  for (int kk = 0; kk < KKn; kk++) {
    float py = GEOM[(size_t)p * NOFF + 2 * kk];
    float px = GEOM[(size_t)p * NOFF + 2 * kk + 1];
    float y0f = floorf(py), x0f = floorf(px);
    float wy = py - y0f, wx = px - x0f;
    int y0 = (int)y0f, x0i = (int)x0f;
    int y1 = y0 + 1, x1i = x0i + 1;
    bool vy0 = (y0 >= 0) && (y0 < Hn), vy1 = (y1 >= 0) && (y1 < Hn);
    bool vx0 = (x0i >= 0) && (x0i < Wn), vx1 = (x1i >= 0) && (x1i < Wn);
    int y0c = vy0 ? y0 : 0, y1c = vy1 ? y1 : 0;
    int x0c = vx0 ? x0i : 0, x1c = vx1 ? x1i : 0;
    float m00 = (vy0 && vx0) ? (1.f - wy) * (1.f - wx) : 0.f;
    float m01 = (vy0 && vx1) ? (1.f - wy) * wx : 0.f;
    float m10 = (vy1 && vx0) ? wy * (1.f - wx) : 0.f;
    float m11 = (vy1 && vx1) ? wy * wx : 0.f;

    const float4* p00 = (const float4*)(XT + pbase + (size_t)(y0c * Wn + x0c) * 64);
    const float4* p01 = (const float4*)(XT + pbase + (size_t)(y0c * Wn + x1c) * 64);
    const float4* p10 = (const float4*)(XT + pbase + (size_t)(y1c * Wn + x0c) * 64);
    const float4* p11 = (const float4*)(XT + pbase + (size_t)(y1c * Wn + x1c) * 64);

    float s[64];
    #pragma unroll
    for (int c4 = 0; c4 < 16; c4++) {
      float4 v00 = p00[c4], v01 = p01[c4], v10 = p10[c4], v11 = p11[c4];
      s[c4 * 4 + 0] = v00.x * m00 + v01.x * m01 + v10.x * m10 + v11.x * m11;
      s[c4 * 4 + 1] = v00.y * m00 + v01.y * m01 + v10.y * m10 + v11.y * m11;
      s[c4 * 4 + 2] = v00.z * m00 + v01.z * m01 + v10.z * m10 + v11.z * m11;
      s[c4 * 4 + 3] = v00.w * m00 + v01.w * m01 + v10.w * m10 + v11.w * m11;
    }

    const float* wk = WT + kk * 64 * 64 + obase * 64;
    #pragma unroll
    for (int o = 0; o < 32; o++) {
      float a = acc[o];
      const float* wr = wk + o * 64;
      #pragma unroll
      for (int c = 0; c < 64; c++) a += wr[c] * s[c];
      acc[o] = a;
    }
  }

  float sk = skip_scale[0];
  const float4* dwp = (const float4*)(DWT + (size_t)p * 64 + obase);
  const float4* xp  = (const float4*)(XT  + (size_t)p * 64 + obase);
  #pragma unroll
  for (int o4 = 0; o4 < 8; o4++) {
    float4 dv = dwp[o4];
    float4 xv = xp[o4];
    float d[4] = {dv.x, dv.y, dv.z, dv.w};
    float xs[4] = {xv.x, xv.y, xv.z, xv.w};
    #pragma unroll
    for (int j = 0; j < 4; j++) {
      int o = obase + o4 * 4 + j;
      float xdw = d[j] * scale[o] + shift[o];
      float res = acc[o4 * 4 + j] + xdw + xs[j] * sk;
      out[(size_t)(b * 64 + o) * HWn + sp] = res;
    }
  }
}

// ---------------------------------------------------------------------------
extern "C" void kernel_launch(void* const* d_in, const int* in_sizes, int n_in,
                              void* d_out, int out_size, void* d_ws, size_t ws_size,
                              hipStream_t stream)
{
  const float* x        = (const float*)d_in[0];
  const float* dw_w     = (const float*)d_in[1];
  const float* dw_b     = (const float*)d_in[2];
  const float* bn_gamma = (const float*)d_in[3];
  const float* bn_beta  = (const float*)d_in[4];
  const float* pw_w     = (const float*)d_in[5];
  const float* pw_b     = (const float*)d_in[6];
  const float* skip     = (const float*)d_in[7];
  const float* deform_w = (const float*)d_in[8];
  const float* deform_b = (const float*)d_in[9];
  float* out = (float*)d_out;
  float* ws  = (float*)d_ws;

  hipMemsetAsync(ws + OFF_SSUM, 0, 2 * 64 * sizeof(float), stream);

  k_wt<<<144, 256, 0, stream>>>(deform_w, ws + OFF_WT);
  k1_dw_transpose<<<512, 128, 0, stream>>>(x, dw_w, dw_b, ws + OFF_XT, ws + OFF_DWT);
  k_stats<<<256, 256, 0, stream>>>(ws + OFF_DWT, ws + OFF_SSUM, ws + OFF_SSQ);
  k2_finalize<<<1, 64, 0, stream>>>(ws + OFF_SSUM, ws + OFF_SSQ, bn_gamma, bn_beta,
                                    ws + OFF_SCALE, ws + OFF_SHIFT);
  k3_offsets<<<256, 256, 0, stream>>>(ws + OFF_DWT, ws + OFF_SCALE, ws + OFF_SHIFT,
                                      pw_w, pw_b, ws + OFF_GEOM);
  k4_deform<<<1024, 128, 0, stream>>>(ws + OFF_XT, ws + OFF_DWT, ws + OFF_GEOM,
                                      ws + OFF_WT, ws + OFF_SCALE, ws + OFF_SHIFT,
                                      deform_b, skip, out);
}

// Round 7
// 466.786 us; speedup vs baseline: 1.7292x; 1.7292x over previous
//
#include <hip/hip_runtime.h>

#define Bn 4
#define Cn 64
#define Hn 128
#define Wn 128
#define HWn (Hn*Wn)          // 16384
#define NPIX (Bn*HWn)        // 65536
#define KKn 9
#define NOFF 18
#define EPSf 1e-5f

// ws layout (float element offsets)
#define OFF_XT    0u
#define OFF_DWT   4194304u
#define OFF_GEOM  8388608u        // GEOM2: [kk][p][2] floats, 1179648
#define OFF_WT    9568256u        // WT2: bf16 [kk][o][c], 73728 shorts = 36864 float slots
#define OFF_SSUM  9605120u
#define OFF_SSQ   9605184u
#define OFF_SCALE 9605248u
#define OFF_SHIFT 9605312u

typedef __attribute__((ext_vector_type(8))) short short8v;
typedef __attribute__((ext_vector_type(4))) float float4v;

// round-to-nearest-even f32 -> bf16 bits
__device__ __forceinline__ unsigned short f2bf(float f) {
  unsigned u = __builtin_bit_cast(unsigned, f);
  u += 0x7fffu + ((u >> 16) & 1u);
  return (unsigned short)(u >> 16);
}

// ---------------------------------------------------------------------------
// K1: depthwise 3x3 conv + bias -> DWT (NHWC f32), and x -> XT (NHWC f32)
__global__ __launch_bounds__(128) void k1_dw_transpose(
    const float* __restrict__ x, const float* __restrict__ dw_w,
    const float* __restrict__ dw_b, float* __restrict__ XT,
    float* __restrict__ DWT)
{
  int p = blockIdx.x * 128 + threadIdx.x;
  int b = p >> 14; int sp = p & 16383; int h = sp >> 7; int w = sp & 127;

  int so[9]; float mval[9];
  #pragma unroll
  for (int t = 0; t < 9; t++) {
    int dy = t / 3 - 1, dx = t % 3 - 1;
    int hh = h + dy, ww = w + dx;
    bool v = (hh >= 0) && (hh < Hn) && (ww >= 0) && (ww < Wn);
    int hc = v ? hh : h; int wc = v ? ww : w;
    so[t] = hc * Wn + wc;
    mval[t] = v ? 1.f : 0.f;
  }
  const float* xb = x + (size_t)b * Cn * HWn;
  for (int c0 = 0; c0 < Cn; c0 += 4) {
    float xcv[4], dwv[4];
    #pragma unroll
    for (int j = 0; j < 4; j++) {
      int c = c0 + j;
      const float* xc = xb + (size_t)c * HWn;
      float acc = dw_b[c];
      #pragma unroll
      for (int t = 0; t < 9; t++) {
        acc += (mval[t] * xc[so[t]]) * dw_w[c * 9 + t];
      }
      dwv[j] = acc;
      xcv[j] = xc[sp];
    }
    *(float4*)(&XT [(size_t)p * 64 + c0]) = make_float4(xcv[0], xcv[1], xcv[2], xcv[3]);
    *(float4*)(&DWT[(size_t)p * 64 + c0]) = make_float4(dwv[0], dwv[1], dwv[2], dwv[3]);
  }
}

// ---------------------------------------------------------------------------
// K_stats: per-channel sum / sumsq over DWT
__global__ __launch_bounds__(256) void k_stats(const float* __restrict__ DWT,
    float* __restrict__ ssum, float* __restrict__ ssq)
{
  int t = threadIdx.x; int c = t & 63; int g = t >> 6;
  float s = 0.f, q = 0.f;
  for (int p = blockIdx.x * 4 + g; p < NPIX; p += gridDim.x * 4) {
    float v = DWT[(size_t)p * 64 + c];
    s += v; q += v * v;
  }
  __shared__ float ls[2][256];
  ls[0][t] = s; ls[1][t] = q;
  __syncthreads();
  if (t < 64) {
    float s0 = ls[0][t] + ls[0][t + 64] + ls[0][t + 128] + ls[0][t + 192];
    float q0 = ls[1][t] + ls[1][t + 64] + ls[1][t + 128] + ls[1][t + 192];
    atomicAdd(&ssum[t], s0);
    atomicAdd(&ssq[t], q0);
  }
}

// ---------------------------------------------------------------------------
// K2: finalize BN -> scale/shift per channel
__global__ void k2_finalize(const float* __restrict__ ssum, const float* __restrict__ ssq,
    const float* __restrict__ gamma, const float* __restrict__ beta,
    float* __restrict__ scale, float* __restrict__ shift)
{
  int c = threadIdx.x;
  float n = (float)NPIX;
  float mean = ssum[c] / n;
  float var = ssq[c] / n - mean * mean;
  float sc = gamma[c] * rsqrtf(var + EPSf);
  scale[c] = sc;
  shift[c] = beta[c] - mean * sc;
}

// ---------------------------------------------------------------------------
// K_wt: deform_w (o,c,kk) f32 -> WT2[kk][o][c] bf16
__global__ __launch_bounds__(256) void k_wt(const float* __restrict__ dwf,
                                            unsigned short* __restrict__ WT2)
{
  int t = blockIdx.x * 256 + threadIdx.x;
  if (t >= 64 * 64 * 9) return;
  int c = t & 63; int o = (t >> 6) & 63; int kk = t >> 12;
  WT2[t] = f2bf(dwf[(o * 64 + c) * 9 + kk]);
}

// ---------------------------------------------------------------------------
// K3: offsets -> sample coordinates GEOM2[kk][p][{py,px}]
__global__ __launch_bounds__(256) void k3_offsets(const float* __restrict__ DWT,
    const float* __restrict__ scale, const float* __restrict__ shift,
    const float* __restrict__ pw_w, const float* __restrict__ pw_b,
    float* __restrict__ GEOM2)
{
  int p = blockIdx.x * 256 + threadIdx.x;
  int sp = p & 16383; int h = sp >> 7; int w = sp & 127;
  float off[NOFF];
  #pragma unroll
  for (int o = 0; o < NOFF; o++) off[o] = pw_b[o];
  const float4* dp = (const float4*)(DWT + (size_t)p * 64);
  #pragma unroll
  for (int c4 = 0; c4 < 16; c4++) {
    float4 d = dp[c4];
    int c = c4 * 4;
    float x0 = d.x * scale[c]     + shift[c];
    float x1 = d.y * scale[c + 1] + shift[c + 1];
    float x2 = d.z * scale[c + 2] + shift[c + 2];
    float x3 = d.w * scale[c + 3] + shift[c + 3];
    #pragma unroll
    for (int o = 0; o < NOFF; o++) {
      const float* pw = pw_w + o * 64 + c;
      off[o] += pw[0] * x0 + pw[1] * x1 + pw[2] * x2 + pw[3] * x3;
    }
  }
  #pragma unroll
  for (int kk = 0; kk < KKn; kk++) {
    float py = (float)h - 1.f + (float)(kk / 3) + off[2 * kk];
    float px = (float)w - 1.f + (float)(kk % 3) + off[2 * kk + 1];
    float2* g = (float2*)(GEOM2 + ((size_t)kk * NPIX + p) * 2);
    *g = make_float2(py, px);
  }
}

// ---------------------------------------------------------------------------
// K4 (MFMA): per block: 64 pixels x 64 outputs, K = 9kk x 64c in bf16.
// Wave w handles n-tile o=[16w,16w+16), m-tiles 0..3 (16 px each).
// A-frag (16x32): lane holds px=l&15, c = ch*32 + 8*(l>>4) + j (8 contiguous k).
// B-frag: lane holds o=16w+(l&15), same 8 contiguous k; from WT2[kk][o][c].
// D: col(o)=l&15, row(px in tile)=4*(l>>4)+r  [m89-verified].
__global__ __launch_bounds__(256) void k4_mfma(
    const float* __restrict__ XT, const float* __restrict__ DWT,
    const float* __restrict__ GEOM2, const unsigned short* __restrict__ WT2,
    const float* __restrict__ scale, const float* __restrict__ shift,
    const float* __restrict__ deform_b, const float* __restrict__ skip_scale,
    float* __restrict__ out)
{
  const int tid = threadIdx.x;
  const int lane = tid & 63;
  const int wv = tid >> 6;        // 0..3 -> n-tile
  const int l15 = lane & 15;
  const int lg = lane >> 4;       // 0..3 -> k-subblock
  const int p0 = blockIdx.x * 64;
  const int b = p0 >> 14;
  const int obase = wv * 16;

  float4v acc[4];
  #pragma unroll
  for (int mt = 0; mt < 4; mt++) acc[mt] = (float4v){0.f, 0.f, 0.f, 0.f};

  const float* xb = XT + (size_t)b * HWn * 64;
  const int c8 = lg * 8;          // lane's channel sub-offset within a 32-chunk

  for (int kk = 0; kk < KKn; kk++) {
    // B fragments for this kk (reused across 4 m-tiles)
    const unsigned short* wtk = WT2 + ((size_t)kk * 64 + obase + l15) * 64;
    short8v bf0 = *(const short8v*)(wtk + c8);
    short8v bf1 = *(const short8v*)(wtk + 32 + c8);

    #pragma unroll
    for (int mt = 0; mt < 4; mt++) {
      int p = p0 + mt * 16 + l15;
      float2 g = *(const float2*)(GEOM2 + ((size_t)kk * NPIX + p) * 2);
      float py = g.x, px = g.y;
      float y0f = floorf(py), x0f = floorf(px);
      float wy = py - y0f, wx = px - x0f;
      int y0 = (int)y0f, x0i = (int)x0f;
      int y1 = y0 + 1, x1i = x0i + 1;
      bool vy0 = (y0 >= 0) && (y0 < Hn), vy1 = (y1 >= 0) && (y1 < Hn);
      bool vx0 = (x0i >= 0) && (x0i < Wn), vx1 = (x1i >= 0) && (x1i < Wn);
      int y0c = vy0 ? y0 : 0, y1c = vy1 ? y1 : 0;
      int x0c = vx0 ? x0i : 0, x1c = vx1 ? x1i : 0;
      float m00 = (vy0 && vx0) ? (1.f - wy) * (1.f - wx) : 0.f;
      float m01 = (vy0 && vx1) ? (1.f - wy) * wx : 0.f;
      float m10 = (vy1 && vx0) ? wy * (1.f - wx) : 0.f;
      float m11 = (vy1 && vx1) ? wy * wx : 0.f;

      const float* b00 = xb + (size_t)((y0c * Wn + x0c) * 64);
      const float* b01 = xb + (size_t)((y0c * Wn + x1c) * 64);
      const float* b10 = xb + (size_t)((y1c * Wn + x0c) * 64);
      const float* b11 = xb + (size_t)((y1c * Wn + x1c) * 64);

      // ch = 0 : channels [c8, c8+8) of chunk 0
      {
        float4v A0 = *(const float4v*)(b00 + c8), A1 = *(const float4v*)(b00 + c8 + 4);
        float4v B0 = *(const float4v*)(b01 + c8), B1 = *(const float4v*)(b01 + c8 + 4);
        float4v C0 = *(const float4v*)(b10 + c8), C1 = *(const float4v*)(b10 + c8 + 4);
        float4v D0 = *(const float4v*)(b11 + c8), D1 = *(const float4v*)(b11 + c8 + 4);
        short8v af;
        #pragma unroll
        for (int j = 0; j < 4; j++) {
          float s = A0[j] * m00 + B0[j] * m01 + C0[j] * m10 + D0[j] * m11;
          af[j] = (short)f2bf(s);
        }
        #pragma unroll
        for (int j = 0; j < 4; j++) {
          float s = A1[j] * m00 + B1[j] * m01 + C1[j] * m10 + D1[j] * m11;
          af[4 + j] = (short)f2bf(s);
        }
        acc[mt] = __builtin_amdgcn_mfma_f32_16x16x32_bf16(af, bf0, acc[mt], 0, 0, 0);
      }
      // ch = 1 : channels [32+c8, 32+c8+8)
      {
        int c = 32 + c8;
        float4v A0 = *(const float4v*)(b00 + c), A1 = *(const float4v*)(b00 + c + 4);
        float4v B0 = *(const float4v*)(b01 + c), B1 = *(const float4v*)(b01 + c + 4);
        float4v C0 = *(const float4v*)(b10 + c), C1 = *(const float4v*)(b10 + c + 4);
        float4v D0 = *(const float4v*)(b11 + c), D1 = *(const float4v*)(b11 + c + 4);
        short8v af;
        #pragma unroll
        for (int j = 0; j < 4; j++) {
          float s = A0[j] * m00 + B0[j] * m01 + C0[j] * m10 + D0[j] * m11;
          af[j] = (short)f2bf(s);
        }
        #pragma unroll
        for (int j = 0; j < 4; j++) {
          float s = A1[j] * m00 + B1[j] * m01 + C1[j] * m10 + D1[j] * m11;
          af[4 + j] = (short)f2bf(s);
        }
        acc[mt] = __builtin_amdgcn_mfma_f32_16x16x32_bf16(af, bf1, acc[mt], 0, 0, 0);
      }
    }
  }

  // Epilogue: out[b][o][sp] = acc + deform_b[o] + DWT*scale+shift + XT*skip
  float sk = skip_scale[0];
  int o = obase + l15;
  float sc = scale[o], sh = shift[o], db = deform_b[o];
  float* outb = out + ((size_t)(b * 64 + o)) * HWn;
  #pragma unroll
  for (int mt = 0; mt < 4; mt++) {
    #pragma unroll
    for (int r = 0; r < 4; r++) {
      int p = p0 + mt * 16 + lg * 4 + r;
      int sp = p & 16383;
      float dv = DWT[(size_t)p * 64 + o];
      float xv = XT[(size_t)p * 64 + o];
      outb[sp] = acc[mt][r] + db + dv * sc + sh + xv * sk;
    }
  }
}

// ---------------------------------------------------------------------------
extern "C" void kernel_launch(void* const* d_in, const int* in_sizes, int n_in,
                              void* d_out, int out_size, void* d_ws, size_t ws_size,
                              hipStream_t stream)
{
  const float* x        = (const float*)d_in[0];
  const float* dw_w     = (const float*)d_in[1];
  const float* dw_b     = (const float*)d_in[2];
  const float* bn_gamma = (const float*)d_in[3];
  const float* bn_beta  = (const float*)d_in[4];
  const float* pw_w     = (const float*)d_in[5];
  const float* pw_b     = (const float*)d_in[6];
  const float* skip     = (const float*)d_in[7];
  const float* deform_w = (const float*)d_in[8];
  const float* deform_b = (const float*)d_in[9];
  float* out = (float*)d_out;
  float* ws  = (float*)d_ws;

  hipMemsetAsync(ws + OFF_SSUM, 0, 2 * 64 * sizeof(float), stream);

  k_wt<<<144, 256, 0, stream>>>(deform_w, (unsigned short*)(ws + OFF_WT));
  k1_dw_transpose<<<512, 128, 0, stream>>>(x, dw_w, dw_b, ws + OFF_XT, ws + OFF_DWT);
  k_stats<<<256, 256, 0, stream>>>(ws + OFF_DWT, ws + OFF_SSUM, ws + OFF_SSQ);
  k2_finalize<<<1, 64, 0, stream>>>(ws + OFF_SSUM, ws + OFF_SSQ, bn_gamma, bn_beta,
                                    ws + OFF_SCALE, ws + OFF_SHIFT);
  k3_offsets<<<256, 256, 0, stream>>>(ws + OFF_DWT, ws + OFF_SCALE, ws + OFF_SHIFT,
                                      pw_w, pw_b, ws + OFF_GEOM);
  k4_mfma<<<1024, 256, 0, stream>>>(ws + OFF_XT, ws + OFF_DWT, ws + OFF_GEOM,
                                    (const unsigned short*)(ws + OFF_WT),
                                    ws + OFF_SCALE, ws + OFF_SHIFT,
                                    deform_b, skip, out);
}

// Round 9
// 311.475 us; speedup vs baseline: 2.5914x; 1.4986x over previous
//
#include <hip/hip_runtime.h>

#define Bn 4
#define Cn 64
#define Hn 128
#define Wn 128
#define HWn (Hn*Wn)          // 16384
#define NPIX (Bn*HWn)        // 65536
#define KKn 9
#define NOFF 18
#define EPSf 1e-5f

// ws layout (float-word offsets)
#define OFF_DWT   0u              // f32 [p][c], 4194304 words
#define OFF_XTH   4194304u        // bf16 [p][c], 4194304 ushorts = 2097152 words
#define OFF_GEOM  6291456u        // f32 [kk][p][2], 1179648 words
#define OFF_WT    7471104u        // bf16 [kk][o][c], 73728 ushorts = 36864 words
#define OFF_SSUM  7507968u
#define OFF_SSQ   7508032u
#define OFF_SCALE 7508096u
#define OFF_SHIFT 7508160u

typedef __attribute__((ext_vector_type(8))) short short8v;
typedef __attribute__((ext_vector_type(8))) unsigned short ushort8v;
typedef __attribute__((ext_vector_type(4))) float float4v;

// round-to-nearest-even f32 -> bf16 bits
__device__ __forceinline__ unsigned short f2bf(float f) {
  unsigned u = __builtin_bit_cast(unsigned, f);
  u += 0x7fffu + ((u >> 16) & 1u);
  return (unsigned short)(u >> 16);
}
__device__ __forceinline__ float b2f(unsigned short u) {
  return __builtin_bit_cast(float, ((unsigned)u) << 16);
}

// ---------------------------------------------------------------------------
// K1v2: depthwise 3x3 conv + bias -> DWT (NHWC f32) and x -> XTH (NHWC bf16),
// with LDS transpose so global stores are c-major coalesced.
// Block = one image row (128 px), 128 threads.
__global__ __launch_bounds__(128) void k1_dw_t2(
    const float* __restrict__ x, const float* __restrict__ dw_w,
    const float* __restrict__ dw_b, unsigned short* __restrict__ XTH,
    float* __restrict__ DWT)
{
  __shared__ float lds_dw[128][33];
  __shared__ float lds_xt[128][33];
  const int t = threadIdx.x;
  const int p = blockIdx.x * 128 + t;
  const int b = p >> 14; const int sp = p & 16383;
  const int h = sp >> 7; const int w = sp & 127;

  int so[9]; float mval[9];
  #pragma unroll
  for (int tt = 0; tt < 9; tt++) {
    int dy = tt / 3 - 1, dx = tt % 3 - 1;
    int hh = h + dy, ww = w + dx;
    bool v = (hh >= 0) && (hh < Hn) && (ww >= 0) && (ww < Wn);
    int hc = v ? hh : h; int wc = v ? ww : w;
    so[tt] = hc * Wn + wc;
    mval[tt] = v ? 1.f : 0.f;
  }
  const float* xb = x + (size_t)b * Cn * HWn;

  for (int half = 0; half < 2; half++) {
    #pragma unroll
    for (int j8 = 0; j8 < 8; j8++) {
      int c0 = half * 32 + j8 * 4;
      #pragma unroll
      for (int j = 0; j < 4; j++) {
        int c = c0 + j;
        const float* xc = xb + (size_t)c * HWn;
        float acc = dw_b[c];
        #pragma unroll
        for (int tt = 0; tt < 9; tt++)
          acc += (mval[tt] * xc[so[tt]]) * dw_w[c * 9 + tt];
        lds_dw[t][j8 * 4 + j] = acc;
        lds_xt[t][j8 * 4 + j] = xc[sp];
      }
    }
    __syncthreads();
    // flush DWT f32: lanes cover 8 c4-groups x 16 px -> contiguous 128B/px
    #pragma unroll
    for (int pass = 0; pass < 8; pass++) {
      int px_l = pass * 16 + (t >> 3);
      int c_l  = (t & 7) * 4;
      float4 v = *(float4*)&lds_dw[px_l][c_l];
      size_t pp = (size_t)blockIdx.x * 128 + px_l;
      *(float4*)&DWT[pp * 64 + half * 32 + c_l] = v;
    }
    // flush XTH bf16: lanes cover 4 c8-groups x 32 px -> contiguous 64B/px
    #pragma unroll
    for (int pass = 0; pass < 4; pass++) {
      int px_l = pass * 32 + (t >> 2);
      int cg   = (t & 3) * 8;
      unsigned pk[4];
      #pragma unroll
      for (int j = 0; j < 4; j++) {
        unsigned short lo = f2bf(lds_xt[px_l][cg + 2 * j]);
        unsigned short hi = f2bf(lds_xt[px_l][cg + 2 * j + 1]);
        pk[j] = (unsigned)lo | ((unsigned)hi << 16);
      }
      size_t pp = (size_t)blockIdx.x * 128 + px_l;
      *(uint4*)&XTH[pp * 64 + half * 32 + cg] = make_uint4(pk[0], pk[1], pk[2], pk[3]);
    }
    __syncthreads();
  }
}

// ---------------------------------------------------------------------------
// K_stats: per-channel sum / sumsq over DWT
__global__ __launch_bounds__(256) void k_stats(const float* __restrict__ DWT,
    float* __restrict__ ssum, float* __restrict__ ssq)
{
  int t = threadIdx.x; int c = t & 63; int g = t >> 6;
  float s = 0.f, q = 0.f;
  for (int p = blockIdx.x * 4 + g; p < NPIX; p += gridDim.x * 4) {
    float v = DWT[(size_t)p * 64 + c];
    s += v; q += v * v;
  }
  __shared__ float ls[2][256];
  ls[0][t] = s; ls[1][t] = q;
  __syncthreads();
  if (t < 64) {
    float s0 = ls[0][t] + ls[0][t + 64] + ls[0][t + 128] + ls[0][t + 192];
    float q0 = ls[1][t] + ls[1][t + 64] + ls[1][t + 128] + ls[1][t + 192];
    atomicAdd(&ssum[t], s0);
    atomicAdd(&ssq[t], q0);
  }
}

// ---------------------------------------------------------------------------
__global__ void k2_finalize(const float* __restrict__ ssum, const float* __restrict__ ssq,
    const float* __restrict__ gamma, const float* __restrict__ beta,
    float* __restrict__ scale, float* __restrict__ shift)
{
  int c = threadIdx.x;
  float n = (float)NPIX;
  float mean = ssum[c] / n;
  float var = ssq[c] / n - mean * mean;
  float sc = gamma[c] * rsqrtf(var + EPSf);
  scale[c] = sc;
  shift[c] = beta[c] - mean * sc;
}

// ---------------------------------------------------------------------------
__global__ __launch_bounds__(256) void k_wt(const float* __restrict__ dwf,
                                            unsigned short* __restrict__ WT2)
{
  int t = blockIdx.x * 256 + threadIdx.x;
  if (t >= 64 * 64 * 9) return;
  int c = t & 63; int o = (t >> 6) & 63; int kk = t >> 12;
  WT2[t] = f2bf(dwf[(o * 64 + c) * 9 + kk]);
}

// ---------------------------------------------------------------------------
__global__ __launch_bounds__(256) void k3_offsets(const float* __restrict__ DWT,
    const float* __restrict__ scale, const float* __restrict__ shift,
    const float* __restrict__ pw_w, const float* __restrict__ pw_b,
    float* __restrict__ GEOM2)
{
  int p = blockIdx.x * 256 + threadIdx.x;
  int sp = p & 16383; int h = sp >> 7; int w = sp & 127;
  float off[NOFF];
  #pragma unroll
  for (int o = 0; o < NOFF; o++) off[o] = pw_b[o];
  const float4* dp = (const float4*)(DWT + (size_t)p * 64);
  #pragma unroll
  for (int c4 = 0; c4 < 16; c4++) {
    float4 d = dp[c4];
    int c = c4 * 4;
    float x0 = d.x * scale[c]     + shift[c];
    float x1 = d.y * scale[c + 1] + shift[c + 1];
    float x2 = d.z * scale[c + 2] + shift[c + 2];
    float x3 = d.w * scale[c + 3] + shift[c + 3];
    #pragma unroll
    for (int o = 0; o < NOFF; o++) {
      const float* pw = pw_w + o * 64 + c;
      off[o] += pw[0] * x0 + pw[1] * x1 + pw[2] * x2 + pw[3] * x3;
    }
  }
  #pragma unroll
  for (int kk = 0; kk < KKn; kk++) {
    float py = (float)h - 1.f + (float)(kk / 3) + off[2 * kk];
    float px = (float)w - 1.f + (float)(kk % 3) + off[2 * kk + 1];
    float2* g = (float2*)(GEOM2 + ((size_t)kk * NPIX + p) * 2);
    *g = make_float2(py, px);
  }
}

// ---------------------------------------------------------------------------
// K4v2 (MFMA, bf16 gathers): 2048 blocks x 32 px, 4 waves each own 16 o.
// XCD-bijective swizzle keeps each XCD on a contiguous half-image (L2-resident
// bf16 XTH: 2 MB/image). A-frag: lane(px=l&15, c=chunk*32+8*(l>>4)+j).
__global__ __launch_bounds__(256) void k4_mfma2(
    const unsigned short* __restrict__ XTH, const float* __restrict__ DWT,
    const float* __restrict__ GEOM2, const unsigned short* __restrict__ WT2,
    const float* __restrict__ scale, const float* __restrict__ shift,
    const float* __restrict__ deform_b, const float* __restrict__ skip_scale,
    float* __restrict__ out)
{
  const int tid = threadIdx.x;
  const int lane = tid & 63;
  const int wv = tid >> 6;
  const int l15 = lane & 15;
  const int lg = lane >> 4;
  const int bid = blockIdx.x;
  const int swz = (bid & 7) * 256 + (bid >> 3);   // 2048 % 8 == 0 -> bijective
  const int p0 = swz * 32;
  const int b = p0 >> 14;
  const int obase = wv * 16;
  const int c8 = lg * 8;

  float4v acc[2];
  acc[0] = (float4v){0.f, 0.f, 0.f, 0.f};
  acc[1] = (float4v){0.f, 0.f, 0.f, 0.f};

  const unsigned short* xb = XTH + (size_t)b * HWn * 64;

  for (int kk = 0; kk < KKn; kk++) {
    const unsigned short* wtk = WT2 + ((size_t)kk * 64 + obase + l15) * 64;
    short8v bf0 = *(const short8v*)(wtk + c8);
    short8v bf1 = *(const short8v*)(wtk + 32 + c8);

    #pragma unroll
    for (int mt = 0; mt < 2; mt++) {
      int p = p0 + mt * 16 + l15;
      float2 g = *(const float2*)(GEOM2 + ((size_t)kk * NPIX + p) * 2);
      float py = g.x, px = g.y;
      float y0f = floorf(py), x0f = floorf(px);
      float wy = py - y0f, wx = px - x0f;
      int y0 = (int)y0f, x0i = (int)x0f;
      int y1 = y0 + 1, x1i = x0i + 1;
      bool vy0 = (y0 >= 0) && (y0 < Hn), vy1 = (y1 >= 0) && (y1 < Hn);
      bool vx0 = (x0i >= 0) && (x0i < Wn), vx1 = (x1i >= 0) && (x1i < Wn);
      int y0c = vy0 ? y0 : 0, y1c = vy1 ? y1 : 0;
      int x0c = vx0 ? x0i : 0, x1c = vx1 ? x1i : 0;
      float m00 = (vy0 && vx0) ? (1.f - wy) * (1.f - wx) : 0.f;
      float m01 = (vy0 && vx1) ? (1.f - wy) * wx : 0.f;
      float m10 = (vy1 && vx0) ? wy * (1.f - wx) : 0.f;
      float m11 = (vy1 && vx1) ? wy * wx : 0.f;

      const unsigned short* b00 = xb + (size_t)((y0c * Wn + x0c) * 64);
      const unsigned short* b01 = xb + (size_t)((y0c * Wn + x1c) * 64);
      const unsigned short* b10 = xb + (size_t)((y1c * Wn + x0c) * 64);
      const unsigned short* b11 = xb + (size_t)((y1c * Wn + x1c) * 64);

      // chunk 0: channels [c8, c8+8)
      {
        ushort8v u00 = *(const ushort8v*)(b00 + c8);
        ushort8v u01 = *(const ushort8v*)(b01 + c8);
        ushort8v u10 = *(const ushort8v*)(b10 + c8);
        ushort8v u11 = *(const ushort8v*)(b11 + c8);
        short8v af;
        #pragma unroll
        for (int j = 0; j < 8; j++) {
          float s = b2f(u00[j]) * m00 + b2f(u01[j]) * m01 +
                    b2f(u10[j]) * m10 + b2f(u11[j]) * m11;
          af[j] = (short)f2bf(s);
        }
        acc[mt] = __builtin_amdgcn_mfma_f32_16x16x32_bf16(af, bf0, acc[mt], 0, 0, 0);
      }
      // chunk 1: channels [32+c8, 32+c8+8)
      {
        ushort8v u00 = *(const ushort8v*)(b00 + 32 + c8);
        ushort8v u01 = *(const ushort8v*)(b01 + 32 + c8);
        ushort8v u10 = *(const ushort8v*)(b10 + 32 + c8);
        ushort8v u11 = *(const ushort8v*)(b11 + 32 + c8);
        short8v af;
        #pragma unroll
        for (int j = 0; j < 8; j++) {
          float s = b2f(u00[j]) * m00 + b2f(u01[j]) * m01 +
                    b2f(u10[j]) * m10 + b2f(u11[j]) * m11;
          af[j] = (short)f2bf(s);
        }
        acc[mt] = __builtin_amdgcn_mfma_f32_16x16x32_bf16(af, bf1, acc[mt], 0, 0, 0);
      }
    }
  }

  // Epilogue
  float sk = skip_scale[0];
  int o = obase + l15;
  float sc = scale[o], sh = shift[o], db = deform_b[o];
  float* outb = out + ((size_t)(b * 64 + o)) * HWn;
  #pragma unroll
  for (int mt = 0; mt < 2; mt++) {
    #pragma unroll
    for (int r = 0; r < 4; r++) {
      int p = p0 + mt * 16 + lg * 4 + r;
      int sp = p & 16383;
      float dv = DWT[(size_t)p * 64 + o];
      float xv = b2f(XTH[(size_t)p * 64 + o]);
      outb[sp] = acc[mt][r] + db + dv * sc + sh + xv * sk;
    }
  }
}

// ---------------------------------------------------------------------------
extern "C" void kernel_launch(void* const* d_in, const int* in_sizes, int n_in,
                              void* d_out, int out_size, void* d_ws, size_t ws_size,
                              hipStream_t stream)
{
  const float* x        = (const float*)d_in[0];
  const float* dw_w     = (const float*)d_in[1];
  const float* dw_b     = (const float*)d_in[2];
  const float* bn_gamma = (const float*)d_in[3];
  const float* bn_beta  = (const float*)d_in[4];
  const float* pw_w     = (const float*)d_in[5];
  const float* pw_b     = (const float*)d_in[6];
  const float* skip     = (const float*)d_in[7];
  const float* deform_w = (const float*)d_in[8];
  const float* deform_b = (const float*)d_in[9];
  float* out = (float*)d_out;
  float* ws  = (float*)d_ws;

  unsigned short* XTH = (unsigned short*)(ws + OFF_XTH);
  unsigned short* WT2 = (unsigned short*)(ws + OFF_WT);

  hipMemsetAsync(ws + OFF_SSUM, 0, 2 * 64 * sizeof(float), stream);

  k_wt<<<144, 256, 0, stream>>>(deform_w, WT2);
  k1_dw_t2<<<512, 128, 0, stream>>>(x, dw_w, dw_b, XTH, ws + OFF_DWT);
  k_stats<<<256, 256, 0, stream>>>(ws + OFF_DWT, ws + OFF_SSUM, ws + OFF_SSQ);
  k2_finalize<<<1, 64, 0, stream>>>(ws + OFF_SSUM, ws + OFF_SSQ, bn_gamma, bn_beta,
                                    ws + OFF_SCALE, ws + OFF_SHIFT);
  k3_offsets<<<256, 256, 0, stream>>>(ws + OFF_DWT, ws + OFF_SCALE, ws + OFF_SHIFT,
                                      pw_w, pw_b, ws + OFF_GEOM);
  k4_mfma2<<<2048, 256, 0, stream>>>(XTH, ws + OFF_DWT, ws + OFF_GEOM, WT2,
                                     ws + OFF_SCALE, ws + OFF_SHIFT,
                                     deform_b, skip, out);
}